// Round 6
// baseline (247.574 us; speedup 1.0000x reference)
//
#include <hip/hip_runtime.h>
#include <stdint.h>

#define NIMG 32
#define WID 384
#define HW 147456            // 384*384
#define TOPK 1000
#define KPAD 1024
#define NBINS 512
#define BIN_SCALEF 512.0f
#define SEGCAP 256
#define CANDCAP 2048
#define THRESH 0.05f
#define PREF_C 0.99f         // count(s>0.99) ~ 1475 +/- 38 per image; checked at runtime
#define NMS_T 0.4f
#define NBLK 18              // scan blocks per image (18*2048 float4 = 147456 floats)

typedef unsigned long long u64;
typedef unsigned int u32;

// ---------------- workspace layout (bytes); everything fully overwritten each launch ----------------
#define PCNT_OFF 0                                   // 576 u32
#define PCAND_OFF 4096                               // 576*256 u64 = 1179648 -> ends 1183744
#define SKEYS_OFF (PCAND_OFF + NIMG*NBLK*SEGCAP*8)   // 32*1024 u64 = 262144  -> ends 1445888
#define BOXES_OFF (SKEYS_OFF + NIMG*KPAD*8)          // 32*1024 float4 = 524288 -> ends 1970176
#define VALID_OFF (BOXES_OFF + NIMG*KPAD*16)         // 32*16 u64 = 4096        -> ends 1974272
#define MDONE_OFF (VALID_OFF + NIMG*16*8)            // 32 u32 (pad 256)        -> ends 1974528
#define MTRX_OFF  (MDONE_OFF + 256)                  // 32*16*1024 u64 = 4 MB

// triangular index for (col-chunk c, row-chunk k), k >= c
#define TRI(c,k) ((c)*16 - ((c)*((c)-1))/2 + (k) - (c))

// ---------- numerics helpers (fp-contraction-proof, matches numpy f32) ----------
__device__ __forceinline__ float area_of(float x0, float y0, float x1, float y1) {
  float a = fmaxf(x1 - x0, 0.0f) * fmaxf(y1 - y0, 0.0f);
  asm volatile("" : "+v"(a));
  return a;
}

__device__ __forceinline__ bool iou_gt(float ax0, float ay0, float ax1, float ay1, float aa,
                                       float bx0, float by0, float bx1, float by1, float ba) {
  float ix1 = fmaxf(ax0, bx0);
  float iy1 = fmaxf(ay0, by0);
  float ix2 = fminf(ax1, bx1);
  float iy2 = fminf(ay1, by1);
  float iw = fmaxf(ix2 - ix1, 0.0f);
  float ih = fmaxf(iy2 - iy1, 0.0f);
  float inter = iw * ih;
  asm volatile("" : "+v"(inter));
  float uni = fmaxf(aa + ba - inter, 1e-9f);
  return (inter / uni) > NMS_T;
}

__device__ __forceinline__ u64 shflxor64(u64 v, int m) {
  int lo = __shfl_xor((int)(u32)v, m, 64);
  int hi = __shfl_xor((int)(u32)(v >> 32), m, 64);
  return ((u64)(u32)hi << 32) | (u32)lo;
}

__device__ __forceinline__ u64 make_key(float s, u32 idx) {
  u32 ord = __float_as_uint(s) | 0x80000000u;   // s > 0 always here
  return ((u64)ord << 32) | (u32)(~idx);        // desc score, ties asc index (lax.top_k)
}

__device__ __forceinline__ int bin_of(float s) {
  int b = (int)(s * BIN_SCALEF);
  return b < 0 ? 0 : (b > NBINS - 1 ? NBINS - 1 : b);
}

// ---------- kernel 1: prefilter collect only (no histogram) ----------
__global__ __launch_bounds__(256) void scan_kernel(const float* __restrict__ cls,
                                                   u32* __restrict__ pcnt,
                                                   u64* __restrict__ pcand) {
  __shared__ u64 lbuf[SEGCAP];
  __shared__ u32 lcnt;
  const int n = blockIdx.y;
  const int tid = threadIdx.x;
  const int lane = tid & 63;
  if (tid == 0) lcnt = 0;
  __syncthreads();

  const float4* src = (const float4*)(cls + (size_t)n * HW) + blockIdx.x * 2048;
  float4 A[8];
#pragma unroll
  for (int v = 0; v < 8; v++) A[v] = src[tid + v * 256];   // 8 loads in flight

  const u64 ltmask = (1ull << lane) - 1ull;
#pragma unroll
  for (int v = 0; v < 8; v++) {
    float ss[4] = {A[v].x, A[v].y, A[v].z, A[v].w};
#pragma unroll
    for (int c = 0; c < 4; c++) {
      float s = ss[c];
      bool pc = s > PREF_C;
      u64 m = __ballot(pc);
      if (m) {
        int ldr = __ffsll(m) - 1;
        u32 wb = 0;
        if (lane == ldr) wb = atomicAdd(&lcnt, (u32)__popcll(m));   // LDS atomic only
        wb = (u32)__shfl((int)wb, ldr, 64);
        if (pc) {
          u32 pos = wb + (u32)__popcll(m & ltmask);
          if (pos < SEGCAP) lbuf[pos] = make_key(s, (u32)((blockIdx.x * 2048 + tid + v * 256) * 4 + c));
        }
      }
    }
  }
  __syncthreads();
  const int seg = n * NBLK + blockIdx.x;
  if (tid == 0) pcnt[seg] = (lcnt > SEGCAP) ? 0xFFFFFFFFu : lcnt;
  u32 c = lcnt < SEGCAP ? lcnt : (u32)SEGCAP;
  u64* pc = pcand + (size_t)seg * SEGCAP;
  for (u32 i = tid; i < c; i += 256) pc[i] = lbuf[i];
}

// reg-chain bitonic levels for stage k (jstart <= 64, via shuffles, no barriers)
#define REGCHAIN(K, JSTART) do {                                            \
    const bool desc_ = ((tid & ((K) >> 1)) == 0);                           \
    for (int j_ = (JSTART); j_ >= 2; j_ >>= 1) {                            \
      int h_ = j_ >> 1;                                                     \
      bool low_ = (tid & h_) == 0;                                          \
      u64 p0_ = shflxor64(e0, h_), p1_ = shflxor64(e1, h_);                 \
      bool tm_ = (low_ == desc_);                                           \
      e0 = tm_ ? (e0 > p0_ ? e0 : p0_) : (e0 < p0_ ? e0 : p0_);             \
      e1 = tm_ ? (e1 > p1_ ? e1 : p1_) : (e1 < p1_ ? e1 : p1_);             \
    }                                                                       \
    { u64 lo_ = e0 < e1 ? e0 : e1, hi_ = e0 < e1 ? e1 : e0;                 \
      e0 = desc_ ? hi_ : lo_; e1 = desc_ ? lo_ : hi_; }                     \
  } while (0)

// ---------- kernel 2: gather candidates + sort; write top-1024 keys ----------
__global__ __launch_bounds__(1024) void sort_kernel(const float* __restrict__ cls,
                                                    const u32* __restrict__ pcnt,
                                                    const u64* __restrict__ pcand,
                                                    u64* __restrict__ skeys) {
  __shared__ u64 skey[CANDCAP];        // 16 KB
  __shared__ u32 scnt[NBLK];
  __shared__ u32 soff[NBLK];
  __shared__ u32 bs[NBINS];            // fallback only
  __shared__ u32 stmp[64];
  __shared__ int stbin;
  __shared__ u32 sflag, sfc;

  const int n = blockIdx.x;
  const int tid = threadIdx.x;
  const int lane = tid & 63;
  const u64 ltmask = (1ull << lane) - 1ull;

  if (tid < NBLK) scnt[tid] = pcnt[n * NBLK + tid];
  skey[tid] = 0ull; skey[tid + 1024] = 0ull;
  if (tid == 0) sfc = 0;
  __syncthreads();
  if (tid == 0) {
    u32 f = 0, off = 0;
    for (int s = 0; s < NBLK; s++) {
      u32 c = scnt[s];
      if (c == 0xFFFFFFFFu) { f = 1; c = 0; }
      soff[s] = off; off += c;
    }
    if (off < TOPK || off > CANDCAP) f = 1;   // prefilter unusable -> exact fallback
    sflag = f;
  }
  __syncthreads();

  if (sflag == 0) {
    // direct placement: prefix offsets known, no atomics
    for (int s = 0; s < NBLK; s++) {
      u32 c = scnt[s];
      if (tid < c) skey[soff[s] + tid] = pcand[(size_t)(n * NBLK + s) * SEGCAP + tid];
    }
  } else {
    // exact fallback (dead path for bench input): LDS histogram + threshold + collect
    for (int i = tid; i < NBINS; i += 1024) bs[i] = 0;
    __syncthreads();
    const float* ci = cls + (size_t)n * HW;
    for (int base = 0; base < HW; base += 1024) {
      float s = ci[base + tid];
      if (s > THRESH) atomicAdd(&bs[bin_of(s)], 1u);
    }
    __syncthreads();
    if (tid < 64) {
      u32 cs = 0;
#pragma unroll
      for (int k2 = 0; k2 < 8; k2++) cs += bs[lane * 8 + k2];
      u32 s = cs;
#pragma unroll
      for (int d = 1; d < 64; d <<= 1) {
        u32 v = (u32)__shfl_down((int)s, d, 64);
        if (lane + d < 64) s += v;
      }
      stmp[lane] = s;
      u64 mask = __ballot(s >= TOPK);
      if (lane == 0) {
        int t = 0;
        if (mask) {
          int L = 63 - __clzll(mask);
          u32 acc = (L < 63) ? stmp[L + 1] : 0;
          for (int b = L * 8 + 7; b >= L * 8; b--) {
            acc += bs[b];
            if (acc >= TOPK) { t = b; break; }
          }
        }
        stbin = t;
      }
    }
    __syncthreads();
    const int t = stbin;
    for (int base = 0; base < HW; base += 1024) {
      int i = base + tid;
      float s = ci[i];
      bool p = (s > THRESH) && (bin_of(s) >= t);
      u64 m = __ballot(p);
      if (m) {
        int ldr = __ffsll(m) - 1;
        u32 wb = 0;
        if (lane == ldr) wb = atomicAdd(&sfc, (u32)__popcll(m));
        wb = (u32)__shfl((int)wb, ldr, 64);
        if (p) { u32 pos = wb + (u32)__popcll(m & ltmask); if (pos < CANDCAP) skey[pos] = make_key(s, (u32)i); }
      }
    }
  }
  __syncthreads();

  // hybrid bitonic sort (2048 keys, 2/thread; shfl for j<=64, LDS for j>=128)
  {
    u64 e0 = skey[2 * tid], e1 = skey[2 * tid + 1];
    REGCHAIN(2, 1); REGCHAIN(4, 2); REGCHAIN(8, 4); REGCHAIN(16, 8);
    REGCHAIN(32, 16); REGCHAIN(64, 32); REGCHAIN(128, 64);
    for (int k = 256; k <= CANDCAP; k <<= 1) {
      skey[2 * tid] = e0; skey[2 * tid + 1] = e1;
      __syncthreads();
      for (int j = k >> 1; j >= 128; j >>= 1) {
        int i = ((tid & ~(j - 1)) << 1) | (tid & (j - 1));
        u64 a = skey[i], b = skey[i + j];
        bool desc = ((i & k) == 0);
        if (desc ? (a < b) : (a > b)) { skey[i] = b; skey[i + j] = a; }
        __syncthreads();
      }
      e0 = skey[2 * tid]; e1 = skey[2 * tid + 1];
      REGCHAIN(k, 64);
    }
    skey[2 * tid] = e0; skey[2 * tid + 1] = e1;
    __syncthreads();
  }

  if (tid < KPAD) skeys[(size_t)n * KPAD + tid] = skey[tid];
}

// ---------- kernel 3: parallel gather + decode; zero mdone ----------
__global__ __launch_bounds__(128) void decode_kernel(const float* __restrict__ reg,
                                                     const u64* __restrict__ skeys,
                                                     float4* __restrict__ gboxes,
                                                     u64* __restrict__ gvalid,
                                                     u32* __restrict__ mdone) {
  const int n = blockIdx.y;
  const int s8 = blockIdx.x;
  const int tid = threadIdx.x;
  const int k = s8 * 128 + tid;
  if (s8 == 0 && tid == 0) mdone[n] = 0;     // stream-ordered before mr_kernel
  u64 key = skeys[(size_t)n * KPAD + k];
  float x0 = 0.f, y0 = 0.f, x1 = 0.f, y1 = 0.f;
  bool val = false;
  if (key != 0ull && k < TOPK) {
    u32 idx = ~(u32)(key & 0xFFFFFFFFull);
    float sv = __uint_as_float((u32)(key >> 32) & 0x7FFFFFFFu);
    int iy = (int)idx / WID;
    int ix = (int)idx - iy * WID;
    float xx = (float)ix * 4.0f;
    float yy = (float)iy * 4.0f;
    const float* rb = reg + (size_t)n * 4 * HW;
    float r0 = rb[idx];
    float r1 = rb[HW + idx];
    float r2 = rb[2 * HW + idx];
    float r3 = rb[3 * HW + idx];
    y0 = yy - r0; x1 = xx + r1; y1 = yy + r2; x0 = xx - r3;
    float wsz = x1 - x0, hsz = y1 - y0;
    val = (sv > THRESH) && (wsz >= 0.0f) && (hsz >= 0.0f);
  }
  gboxes[(size_t)n * KPAD + k] = make_float4(x0, y0, x1, y1);
  u64 m = __ballot(val);
  if ((tid & 63) == 0) gvalid[n * 16 + (k >> 6)] = m;
}

// ---------- kernel 4: suppression matrix + (last block per image) greedy resolve + output ----------
__global__ __launch_bounds__(256) void mr_kernel(const float4* __restrict__ gboxes,
                                                 const u64* __restrict__ gvalid,
                                                 const u64* __restrict__ skeys,
                                                 u64* __restrict__ M,
                                                 u32* __restrict__ mdone,
                                                 float* __restrict__ out) {
  __shared__ float rb[64][4];
  __shared__ float ra[64];
  __shared__ u64 mlds[136 * 64];       // 68 KB: lower word-triangle of M for this image
  __shared__ u64 keepsh[16], srem[16], sval[16];
  __shared__ u32 sticket;
  const int cw = blockIdx.x;           // row chunk 0..15
  const int n  = blockIdx.y;
  const int tid = threadIdx.x;
  const int q = tid >> 6, lane = tid & 63;

  if (tid < 64) {
    float4 b = gboxes[(size_t)n * KPAD + cw * 64 + tid];
    rb[tid][0] = b.x; rb[tid][1] = b.y; rb[tid][2] = b.z; rb[tid][3] = b.w;
    ra[tid] = area_of(b.x, b.y, b.z, b.w);
  }
  __syncthreads();
  // matrix phase: M[n][w][i] bit j = iou(box_i, box_{64w+j}) > T, for w <= cw, i in chunk cw
  for (int w = 0; w <= cw; w++) {
    float4 cbx = gboxes[(size_t)n * KPAD + w * 64 + lane];
    float carea = area_of(cbx.x, cbx.y, cbx.z, cbx.w);
    u32 alo = 0, ahi = 0;
#pragma unroll
    for (int r = 0; r < 16; r++) {
      int i = q * 16 + r;
      bool pred = iou_gt(rb[i][0], rb[i][1], rb[i][2], rb[i][3], ra[i],
                         cbx.x, cbx.y, cbx.z, cbx.w, carea);
      u64 m = __ballot(pred);
      if (lane == r) { alo = (u32)m; ahi = (u32)(m >> 32); }
    }
    if (lane < 16)
      M[(((size_t)n * 16 + w) << 10) + cw * 64 + q * 16 + lane] = ((u64)ahi << 32) | alo;
  }
  __threadfence();                                   // release M writes to device scope
  if (tid == 0) sticket = atomicAdd(&mdone[n], 1u);  // device-scope by default
  __syncthreads();
  if (sticket != 15) return;                         // not the last block for this image
  __threadfence();                                   // acquire all 16 blocks' M writes

  // resolve phase (last block only): preload M triangle into LDS (4 waves round-robin)
  {
    int cnt2 = 0;
    for (int c = 0; c < 16; c++)
      for (int k = c; k < 16; k++) {
        if ((cnt2 & 3) == q)
          mlds[cnt2 * 64 + lane] = M[(((size_t)n * 16 + c) << 10) + k * 64 + lane];
        cnt2++;
      }
  }
  if (tid < 16) { sval[tid] = gvalid[n * 16 + tid]; srem[tid] = 0ull; keepsh[tid] = 0ull; }
  __syncthreads();

  if (tid < 64) {
    for (int c = 0; c < 16; c++) {
      u64 diag = mlds[TRI(c, c) * 64 + lane];        // row lane of chunk c vs cols chunk c
      u64 alive;
      {
        u64 a = sval[c] & ~srem[c];
        u32 alo2 = __builtin_amdgcn_readfirstlane((u32)a);
        u32 ahi2 = __builtin_amdgcn_readfirstlane((u32)(a >> 32));
        alive = ((u64)ahi2 << 32) | alo2;
      }
      // serial intra resolve via readlane (lane i holds row i)
      u32 rlo = (u32)diag, rhi = (u32)(diag >> 32);
      u64 cur = alive;
      while (cur) {
        int i = __ffsll(cur) - 1;
        u32 rl = __builtin_amdgcn_readlane(rlo, i);
        u32 rh = __builtin_amdgcn_readlane(rhi, i);
        u64 rowi = ((u64)rh << 32) | rl;
        u64 lowmask = (i == 63) ? ~0ull : ((1ull << (i + 1)) - 1ull);
        rowi &= ~lowmask;
        alive &= ~rowi;
        cur &= ~rowi;
        cur &= cur - 1;
      }
      if (lane == 0) keepsh[c] = alive;
      const u64 K = alive;
      // cross-chunk: row (64k+lane) suppressed iff it overlaps any kept box of chunk c (symmetry)
      for (int k = c + 1; k < 16; k++) {
        bool sup = (mlds[TRI(c, k) * 64 + lane] & K) != 0ull;
        u64 mres = __ballot(sup);
        if (lane == 0) srem[k] |= mres;
      }
    }
  }
  __syncthreads();

  // output: 256 threads x 4 rounds
#pragma unroll
  for (int r = 0; r < 4; r++) {
    int k = r * 256 + tid;
    u64 kb = (keepsh[k >> 6] >> (k & 63)) & 1ull;
    float4 b = gboxes[(size_t)n * KPAD + k];
    u64 key = skeys[(size_t)n * KPAD + k];
    float s = __uint_as_float((u32)(key >> 32) & 0x7FFFFFFFu);
    if (k < TOPK) {
      float f = (float)kb;
      size_t ob = (size_t)n * (TOPK * 5) + (size_t)k * 5;
      out[ob + 0] = kb ? b.x : 0.0f;
      out[ob + 1] = kb ? b.y : 0.0f;
      out[ob + 2] = kb ? b.z : 0.0f;
      out[ob + 3] = kb ? b.w : 0.0f;
      out[ob + 4] = kb ? s : 0.0f;
      out[(size_t)NIMG * TOPK * 5 + (size_t)n * TOPK + k] = f;
    }
  }
}

extern "C" void kernel_launch(void* const* d_in, const int* in_sizes, int n_in,
                              void* d_out, int out_size, void* d_ws, size_t ws_size,
                              hipStream_t stream) {
  const float* cls = (const float*)d_in[0];   // (32,1,384,384) f32
  const float* reg = (const float*)d_in[1];   // (32,4,384,384) f32
  float* out = (float*)d_out;                 // 160000 (out) + 32000 (keep) f32

  uint8_t* ws = (uint8_t*)d_ws;
  u32* pcnt = (u32*)(ws + PCNT_OFF);
  u64* pcand = (u64*)(ws + PCAND_OFF);
  u64* skeys = (u64*)(ws + SKEYS_OFF);
  float4* gboxes = (float4*)(ws + BOXES_OFF);
  u64* gvalid = (u64*)(ws + VALID_OFF);
  u32* mdone = (u32*)(ws + MDONE_OFF);
  u64* M = (u64*)(ws + MTRX_OFF);

  scan_kernel<<<dim3(NBLK, NIMG), 256, 0, stream>>>(cls, pcnt, pcand);
  sort_kernel<<<NIMG, 1024, 0, stream>>>(cls, pcnt, pcand, skeys);
  decode_kernel<<<dim3(8, NIMG), 128, 0, stream>>>(reg, skeys, gboxes, gvalid, mdone);
  mr_kernel<<<dim3(16, NIMG), 256, 0, stream>>>(gboxes, gvalid, skeys, M, mdone, out);
}

// Round 7
// 210.067 us; speedup vs baseline: 1.1785x; 1.1785x over previous
//
#include <hip/hip_runtime.h>
#include <stdint.h>

#define NIMG 32
#define WID 384
#define HW 147456            // 384*384
#define TOPK 1000
#define KPAD 1024
#define NBINS 512
#define BIN_SCALEF 512.0f
#define SEGCAP 256
#define CANDCAP 2048
#define THRESH 0.05f
#define PREF_C 0.99f         // count(s>0.99) ~ 1475 +/- 38 per image; runtime-checked, exact fallback
#define NMS_T 0.4f
#define NBLK 18              // scan blocks per image (18*2048 float4 = 147456 floats)

typedef unsigned long long u64;
typedef unsigned int u32;

// ---------------- workspace layout (bytes); everything fully overwritten each launch ----------------
#define PCNT_OFF 0                                   // 576 u32
#define PCAND_OFF 4096                               // 576*256 u64 = 1179648 -> ends 1183744
#define SKEYS_OFF (PCAND_OFF + NIMG*NBLK*SEGCAP*8)   // 32*1024 u64 = 262144  -> ends 1445888
#define BOXES_OFF (SKEYS_OFF + NIMG*KPAD*8)          // 32*1024 float4 = 524288 -> ends 1970176
#define VALID_OFF (BOXES_OFF + NIMG*KPAD*16)         // 32*16 u64 = 4096        -> ends 1974272
#define MTRX_OFF  (VALID_OFF + NIMG*16*8 + 256)      // 32*16*1024 u64 = 4 MB

// triangular index for (col-chunk c, row-chunk k), k >= c
#define TRI(c,k) ((c)*16 - ((c)*((c)-1))/2 + (k) - (c))

// ---------- numerics helpers (fp-contraction-proof, matches numpy f32) ----------
__device__ __forceinline__ float area_of(float x0, float y0, float x1, float y1) {
  float a = fmaxf(x1 - x0, 0.0f) * fmaxf(y1 - y0, 0.0f);
  asm volatile("" : "+v"(a));
  return a;
}

__device__ __forceinline__ bool iou_gt(float ax0, float ay0, float ax1, float ay1, float aa,
                                       float bx0, float by0, float bx1, float by1, float ba) {
  float ix1 = fmaxf(ax0, bx0);
  float iy1 = fmaxf(ay0, by0);
  float ix2 = fminf(ax1, bx1);
  float iy2 = fminf(ay1, by1);
  float iw = fmaxf(ix2 - ix1, 0.0f);
  float ih = fmaxf(iy2 - iy1, 0.0f);
  float inter = iw * ih;
  asm volatile("" : "+v"(inter));
  float uni = fmaxf(aa + ba - inter, 1e-9f);
  return (inter / uni) > NMS_T;
}

__device__ __forceinline__ u64 shflxor64(u64 v, int m) {
  int lo = __shfl_xor((int)(u32)v, m, 64);
  int hi = __shfl_xor((int)(u32)(v >> 32), m, 64);
  return ((u64)(u32)hi << 32) | (u32)lo;
}

__device__ __forceinline__ u64 make_key(float s, u32 idx) {
  u32 ord = __float_as_uint(s) | 0x80000000u;   // s > 0 always here
  return ((u64)ord << 32) | (u32)(~idx);        // desc score, ties asc index (lax.top_k)
}

__device__ __forceinline__ int bin_of(float s) {
  int b = (int)(s * BIN_SCALEF);
  return b < 0 ? 0 : (b > NBINS - 1 ? NBINS - 1 : b);
}

// ---------- kernel 1: prefilter collect only (no histogram) ----------
__global__ __launch_bounds__(256) void scan_kernel(const float* __restrict__ cls,
                                                   u32* __restrict__ pcnt,
                                                   u64* __restrict__ pcand) {
  __shared__ u64 lbuf[SEGCAP];
  __shared__ u32 lcnt;
  const int n = blockIdx.y;
  const int tid = threadIdx.x;
  const int lane = tid & 63;
  if (tid == 0) lcnt = 0;
  __syncthreads();

  const float4* src = (const float4*)(cls + (size_t)n * HW) + blockIdx.x * 2048;
  float4 A[8];
#pragma unroll
  for (int v = 0; v < 8; v++) A[v] = src[tid + v * 256];   // 8 loads in flight

  const u64 ltmask = (1ull << lane) - 1ull;
#pragma unroll
  for (int v = 0; v < 8; v++) {
    float ss[4] = {A[v].x, A[v].y, A[v].z, A[v].w};
#pragma unroll
    for (int c = 0; c < 4; c++) {
      float s = ss[c];
      bool pc = s > PREF_C;
      u64 m = __ballot(pc);
      if (m) {
        int ldr = __ffsll(m) - 1;
        u32 wb = 0;
        if (lane == ldr) wb = atomicAdd(&lcnt, (u32)__popcll(m));   // LDS atomic only
        wb = (u32)__shfl((int)wb, ldr, 64);
        if (pc) {
          u32 pos = wb + (u32)__popcll(m & ltmask);
          if (pos < SEGCAP) lbuf[pos] = make_key(s, (u32)((blockIdx.x * 2048 + tid + v * 256) * 4 + c));
        }
      }
    }
  }
  __syncthreads();
  const int seg = n * NBLK + blockIdx.x;
  if (tid == 0) pcnt[seg] = (lcnt > SEGCAP) ? 0xFFFFFFFFu : lcnt;
  u32 c = lcnt < SEGCAP ? lcnt : (u32)SEGCAP;
  u64* pc = pcand + (size_t)seg * SEGCAP;
  for (u32 i = tid; i < c; i += 256) pc[i] = lbuf[i];
}

// reg-chain bitonic levels for stage k (jstart <= 64, via shuffles, no barriers)
#define REGCHAIN(K, JSTART) do {                                            \
    const bool desc_ = ((tid & ((K) >> 1)) == 0);                           \
    for (int j_ = (JSTART); j_ >= 2; j_ >>= 1) {                            \
      int h_ = j_ >> 1;                                                     \
      bool low_ = (tid & h_) == 0;                                          \
      u64 p0_ = shflxor64(e0, h_), p1_ = shflxor64(e1, h_);                 \
      bool tm_ = (low_ == desc_);                                           \
      e0 = tm_ ? (e0 > p0_ ? e0 : p0_) : (e0 < p0_ ? e0 : p0_);             \
      e1 = tm_ ? (e1 > p1_ ? e1 : p1_) : (e1 < p1_ ? e1 : p1_);             \
    }                                                                       \
    { u64 lo_ = e0 < e1 ? e0 : e1, hi_ = e0 < e1 ? e1 : e0;                 \
      e0 = desc_ ? hi_ : lo_; e1 = desc_ ? lo_ : hi_; }                     \
  } while (0)

// ---------- kernel 2: gather candidates + sort; write top-1024 keys ----------
__global__ __launch_bounds__(1024) void sort_kernel(const float* __restrict__ cls,
                                                    const u32* __restrict__ pcnt,
                                                    const u64* __restrict__ pcand,
                                                    u64* __restrict__ skeys) {
  __shared__ u64 skey[CANDCAP];        // 16 KB
  __shared__ u32 scnt[NBLK];
  __shared__ u32 soff[NBLK];
  __shared__ u32 bs[NBINS];            // fallback only
  __shared__ u32 stmp[64];
  __shared__ int stbin;
  __shared__ u32 sflag, sfc;

  const int n = blockIdx.x;
  const int tid = threadIdx.x;
  const int lane = tid & 63;
  const u64 ltmask = (1ull << lane) - 1ull;

  if (tid < NBLK) scnt[tid] = pcnt[n * NBLK + tid];
  skey[tid] = 0ull; skey[tid + 1024] = 0ull;
  if (tid == 0) sfc = 0;
  __syncthreads();
  if (tid == 0) {
    u32 f = 0, off = 0;
    for (int s = 0; s < NBLK; s++) {
      u32 c = scnt[s];
      if (c == 0xFFFFFFFFu) { f = 1; c = 0; }
      soff[s] = off; off += c;
    }
    if (off < TOPK || off > CANDCAP) f = 1;   // prefilter unusable -> exact fallback
    sflag = f;
  }
  __syncthreads();

  if (sflag == 0) {
    // direct placement: prefix offsets known, no atomics
    for (int s = 0; s < NBLK; s++) {
      u32 c = scnt[s];
      if (tid < c) skey[soff[s] + tid] = pcand[(size_t)(n * NBLK + s) * SEGCAP + tid];
    }
  } else {
    // exact fallback (dead path for bench input): LDS histogram + threshold + collect
    for (int i = tid; i < NBINS; i += 1024) bs[i] = 0;
    __syncthreads();
    const float* ci = cls + (size_t)n * HW;
    for (int base = 0; base < HW; base += 1024) {
      float s = ci[base + tid];
      if (s > THRESH) atomicAdd(&bs[bin_of(s)], 1u);
    }
    __syncthreads();
    if (tid < 64) {
      u32 cs = 0;
#pragma unroll
      for (int k2 = 0; k2 < 8; k2++) cs += bs[lane * 8 + k2];
      u32 s = cs;
#pragma unroll
      for (int d = 1; d < 64; d <<= 1) {
        u32 v = (u32)__shfl_down((int)s, d, 64);
        if (lane + d < 64) s += v;
      }
      stmp[lane] = s;
      u64 mask = __ballot(s >= TOPK);
      if (lane == 0) {
        int t = 0;
        if (mask) {
          int L = 63 - __clzll(mask);
          u32 acc = (L < 63) ? stmp[L + 1] : 0;
          for (int b = L * 8 + 7; b >= L * 8; b--) {
            acc += bs[b];
            if (acc >= TOPK) { t = b; break; }
          }
        }
        stbin = t;
      }
    }
    __syncthreads();
    const int t = stbin;
    for (int base = 0; base < HW; base += 1024) {
      int i = base + tid;
      float s = ci[i];
      bool p = (s > THRESH) && (bin_of(s) >= t);
      u64 m = __ballot(p);
      if (m) {
        int ldr = __ffsll(m) - 1;
        u32 wb = 0;
        if (lane == ldr) wb = atomicAdd(&sfc, (u32)__popcll(m));
        wb = (u32)__shfl((int)wb, ldr, 64);
        if (p) { u32 pos = wb + (u32)__popcll(m & ltmask); if (pos < CANDCAP) skey[pos] = make_key(s, (u32)i); }
      }
    }
  }
  __syncthreads();

  // hybrid bitonic sort (2048 keys, 2/thread; shfl for j<=64, LDS for j>=128)
  {
    u64 e0 = skey[2 * tid], e1 = skey[2 * tid + 1];
    REGCHAIN(2, 1); REGCHAIN(4, 2); REGCHAIN(8, 4); REGCHAIN(16, 8);
    REGCHAIN(32, 16); REGCHAIN(64, 32); REGCHAIN(128, 64);
    for (int k = 256; k <= CANDCAP; k <<= 1) {
      skey[2 * tid] = e0; skey[2 * tid + 1] = e1;
      __syncthreads();
      for (int j = k >> 1; j >= 128; j >>= 1) {
        int i = ((tid & ~(j - 1)) << 1) | (tid & (j - 1));
        u64 a = skey[i], b = skey[i + j];
        bool desc = ((i & k) == 0);
        if (desc ? (a < b) : (a > b)) { skey[i] = b; skey[i + j] = a; }
        __syncthreads();
      }
      e0 = skey[2 * tid]; e1 = skey[2 * tid + 1];
      REGCHAIN(k, 64);
    }
    skey[2 * tid] = e0; skey[2 * tid + 1] = e1;
    __syncthreads();
  }

  if (tid < KPAD) skeys[(size_t)n * KPAD + tid] = skey[tid];
}

// ---------- kernel 3: parallel gather + decode ----------
__global__ __launch_bounds__(128) void decode_kernel(const float* __restrict__ reg,
                                                     const u64* __restrict__ skeys,
                                                     float4* __restrict__ gboxes,
                                                     u64* __restrict__ gvalid) {
  const int n = blockIdx.y;
  const int s8 = blockIdx.x;
  const int tid = threadIdx.x;
  const int k = s8 * 128 + tid;
  u64 key = skeys[(size_t)n * KPAD + k];
  float x0 = 0.f, y0 = 0.f, x1 = 0.f, y1 = 0.f;
  bool val = false;
  if (key != 0ull && k < TOPK) {
    u32 idx = ~(u32)(key & 0xFFFFFFFFull);
    float sv = __uint_as_float((u32)(key >> 32) & 0x7FFFFFFFu);
    int iy = (int)idx / WID;
    int ix = (int)idx - iy * WID;
    float xx = (float)ix * 4.0f;
    float yy = (float)iy * 4.0f;
    const float* rb = reg + (size_t)n * 4 * HW;
    float r0 = rb[idx];
    float r1 = rb[HW + idx];
    float r2 = rb[2 * HW + idx];
    float r3 = rb[3 * HW + idx];
    y0 = yy - r0; x1 = xx + r1; y1 = yy + r2; x0 = xx - r3;
    float wsz = x1 - x0, hsz = y1 - y0;
    val = (sv > THRESH) && (wsz >= 0.0f) && (hsz >= 0.0f);
  }
  gboxes[(size_t)n * KPAD + k] = make_float4(x0, y0, x1, y1);
  u64 m = __ballot(val);
  if ((tid & 63) == 0) gvalid[n * 16 + (k >> 6)] = m;
}

// ---------- kernel 4: chip-wide suppression bit-matrix (lower word-triangle) ----------
// M[n][w][i] bit j = iou(box_i, box_{64w+j}) > NMS_T, computed for w <= i>>6.
__global__ __launch_bounds__(256) void matrix_kernel(const float4* __restrict__ gboxes,
                                                     u64* __restrict__ M) {
  __shared__ float rb[64][4];
  __shared__ float ra[64];
  const int cw = blockIdx.x;       // row chunk 0..15
  const int n  = blockIdx.y;
  const int tid = threadIdx.x;
  const int q = tid >> 6, lane = tid & 63;
  if (tid < 64) {
    float4 b = gboxes[(size_t)n * KPAD + cw * 64 + tid];
    rb[tid][0] = b.x; rb[tid][1] = b.y; rb[tid][2] = b.z; rb[tid][3] = b.w;
    ra[tid] = area_of(b.x, b.y, b.z, b.w);
  }
  __syncthreads();
  for (int w = 0; w <= cw; w++) {
    float4 cbx = gboxes[(size_t)n * KPAD + w * 64 + lane];
    float carea = area_of(cbx.x, cbx.y, cbx.z, cbx.w);
    u32 alo = 0, ahi = 0;
#pragma unroll
    for (int r = 0; r < 16; r++) {
      int i = q * 16 + r;          // row within chunk
      bool pred = iou_gt(rb[i][0], rb[i][1], rb[i][2], rb[i][3], ra[i],
                         cbx.x, cbx.y, cbx.z, cbx.w, carea);
      u64 m = __ballot(pred);
      if (lane == r) { alo = (u32)m; ahi = (u32)(m >> 32); }   // stash row r into lane r
    }
    if (lane < 16)
      M[(((size_t)n * 16 + w) << 10) + cw * 64 + q * 16 + lane] = ((u64)ahi << 32) | alo;
  }
}

// ---------- kernel 5: resolve — 4-wave LDS preload + 1-wave bit-op greedy + output ----------
__global__ __launch_bounds__(256) void resolve_kernel(const float4* __restrict__ gboxes,
                                                      const u64* __restrict__ gvalid,
                                                      const u64* __restrict__ skeys,
                                                      const u64* __restrict__ M,
                                                      float* __restrict__ out) {
  __shared__ u64 mlds[136 * 64];       // 68 KB: lower word-triangle of M for this image
  __shared__ u64 keepsh[16], srem[16], sval[16];
  const int n = blockIdx.x;
  const int tid = threadIdx.x;
  const int lane = tid & 63;

  // cooperative preload: col-chunk c's region is rows c*64..1023 (contiguous in M)
  for (int c = 0; c < 16; c++) {
    const u64* src = M + (((size_t)n * 16 + c) << 10) + c * 64;
    u64* dst = mlds + TRI(c, c) * 64;
    const int len = (16 - c) * 64;
    for (int j = tid; j < len; j += 256) dst[j] = src[j];
  }
  if (tid < 16) { sval[tid] = gvalid[n * 16 + tid]; srem[tid] = 0ull; keepsh[tid] = 0ull; }
  __syncthreads();

  if (tid < 64) {
    for (int c = 0; c < 16; c++) {
      u64 diag = mlds[TRI(c, c) * 64 + lane];        // row lane of chunk c vs cols of chunk c
      u64 alive;
      {
        u64 a = sval[c] & ~srem[c];
        u32 alo2 = __builtin_amdgcn_readfirstlane((u32)a);
        u32 ahi2 = __builtin_amdgcn_readfirstlane((u32)(a >> 32));
        alive = ((u64)ahi2 << 32) | alo2;
      }
      // serial intra resolve via readlane (lane i holds row i)
      u32 rlo = (u32)diag, rhi = (u32)(diag >> 32);
      u64 cur = alive;
      while (cur) {
        int i = __ffsll(cur) - 1;
        u32 rl = __builtin_amdgcn_readlane(rlo, i);
        u32 rh = __builtin_amdgcn_readlane(rhi, i);
        u64 rowi = ((u64)rh << 32) | rl;
        u64 lowmask = (i == 63) ? ~0ull : ((1ull << (i + 1)) - 1ull);
        rowi &= ~lowmask;                            // suppress only j > i
        alive &= ~rowi;
        cur &= ~rowi;
        cur &= cur - 1;
      }
      if (lane == 0) keepsh[c] = alive;
      const u64 K = alive;
      // cross-chunk: row (64k+lane) suppressed iff it overlaps any kept box of chunk c (symmetry)
      for (int k = c + 1; k < 16; k++) {
        bool sup = (mlds[TRI(c, k) * 64 + lane] & K) != 0ull;
        u64 mres = __ballot(sup);
        if (lane == 0) srem[k] |= mres;
      }
    }
  }
  __syncthreads();

  // output: 256 threads x 4 rounds
#pragma unroll
  for (int r = 0; r < 4; r++) {
    int k = r * 256 + tid;
    u64 kb = (keepsh[k >> 6] >> (k & 63)) & 1ull;
    float4 b = gboxes[(size_t)n * KPAD + k];
    u64 key = skeys[(size_t)n * KPAD + k];
    float s = __uint_as_float((u32)(key >> 32) & 0x7FFFFFFFu);
    if (k < TOPK) {
      float f = (float)kb;
      size_t ob = (size_t)n * (TOPK * 5) + (size_t)k * 5;
      out[ob + 0] = kb ? b.x : 0.0f;
      out[ob + 1] = kb ? b.y : 0.0f;
      out[ob + 2] = kb ? b.z : 0.0f;
      out[ob + 3] = kb ? b.w : 0.0f;
      out[ob + 4] = kb ? s : 0.0f;
      out[(size_t)NIMG * TOPK * 5 + (size_t)n * TOPK + k] = f;
    }
  }
}

extern "C" void kernel_launch(void* const* d_in, const int* in_sizes, int n_in,
                              void* d_out, int out_size, void* d_ws, size_t ws_size,
                              hipStream_t stream) {
  const float* cls = (const float*)d_in[0];   // (32,1,384,384) f32
  const float* reg = (const float*)d_in[1];   // (32,4,384,384) f32
  float* out = (float*)d_out;                 // 160000 (out) + 32000 (keep) f32

  uint8_t* ws = (uint8_t*)d_ws;
  u32* pcnt = (u32*)(ws + PCNT_OFF);
  u64* pcand = (u64*)(ws + PCAND_OFF);
  u64* skeys = (u64*)(ws + SKEYS_OFF);
  float4* gboxes = (float4*)(ws + BOXES_OFF);
  u64* gvalid = (u64*)(ws + VALID_OFF);
  u64* M = (u64*)(ws + MTRX_OFF);

  scan_kernel<<<dim3(NBLK, NIMG), 256, 0, stream>>>(cls, pcnt, pcand);
  sort_kernel<<<NIMG, 1024, 0, stream>>>(cls, pcnt, pcand, skeys);
  decode_kernel<<<dim3(8, NIMG), 128, 0, stream>>>(reg, skeys, gboxes, gvalid);
  matrix_kernel<<<dim3(16, NIMG), 256, 0, stream>>>(gboxes, M);
  resolve_kernel<<<NIMG, 256, 0, stream>>>(gboxes, gvalid, skeys, M, out);
}

// Round 8
// 173.219 us; speedup vs baseline: 1.4293x; 1.2127x over previous
//
#include <hip/hip_runtime.h>
#include <stdint.h>

#define NIMG 32
#define WID 384
#define HW 147456            // 384*384
#define TOPK 1000
#define KPAD 1024
#define NBINS 512
#define BIN_SCALEF 512.0f
#define SEGCAP 256
#define CANDCAP 2048
#define THRESH 0.05f
#define PREF_C 0.99f         // count(s>0.99) ~ 1475 +/- 38 per image; runtime-checked, exact fallback
#define NMS_T 0.4f
#define NBLK 18              // scan blocks per image (18*2048 float4 = 147456 floats)

typedef unsigned long long u64;
typedef unsigned int u32;

// ---------------- workspace layout (bytes); everything fully overwritten each launch ----------------
#define PCNT_OFF 0                                   // 576 u32
#define PCAND_OFF 4096                               // 576*256 u64 = 1179648 -> ends 1183744
#define SKEYS_OFF (PCAND_OFF + NIMG*NBLK*SEGCAP*8)   // 32*1024 u64 = 262144  -> ends 1445888
#define BOXES_OFF (SKEYS_OFF + NIMG*KPAD*8)          // 32*1024 float4 = 524288 -> ends 1970176

// ---------- numerics helpers (fp-contraction-proof, matches numpy f32) ----------
__device__ __forceinline__ float area_of(float x0, float y0, float x1, float y1) {
  float a = fmaxf(x1 - x0, 0.0f) * fmaxf(y1 - y0, 0.0f);
  asm volatile("" : "+v"(a));
  return a;
}

__device__ __forceinline__ bool iou_gt(float ax0, float ay0, float ax1, float ay1, float aa,
                                       float bx0, float by0, float bx1, float by1, float ba) {
  float ix1 = fmaxf(ax0, bx0);
  float iy1 = fmaxf(ay0, by0);
  float ix2 = fminf(ax1, bx1);
  float iy2 = fminf(ay1, by1);
  float iw = fmaxf(ix2 - ix1, 0.0f);
  float ih = fmaxf(iy2 - iy1, 0.0f);
  float inter = iw * ih;
  asm volatile("" : "+v"(inter));
  float uni = fmaxf(aa + ba - inter, 1e-9f);
  return (inter / uni) > NMS_T;
}

__device__ __forceinline__ u64 shflxor64(u64 v, int m) {
  int lo = __shfl_xor((int)(u32)v, m, 64);
  int hi = __shfl_xor((int)(u32)(v >> 32), m, 64);
  return ((u64)(u32)hi << 32) | (u32)lo;
}

__device__ __forceinline__ u64 make_key(float s, u32 idx) {
  u32 ord = __float_as_uint(s) | 0x80000000u;   // s > 0 always here
  return ((u64)ord << 32) | (u32)(~idx);        // desc score, ties asc index (lax.top_k)
}

__device__ __forceinline__ int bin_of(float s) {
  int b = (int)(s * BIN_SCALEF);
  return b < 0 ? 0 : (b > NBINS - 1 ? NBINS - 1 : b);
}

// ---------- kernel 1: prefilter collect only (no histogram) ----------
__global__ __launch_bounds__(256) void scan_kernel(const float* __restrict__ cls,
                                                   u32* __restrict__ pcnt,
                                                   u64* __restrict__ pcand) {
  __shared__ u64 lbuf[SEGCAP];
  __shared__ u32 lcnt;
  const int n = blockIdx.y;
  const int tid = threadIdx.x;
  const int lane = tid & 63;
  if (tid == 0) lcnt = 0;
  __syncthreads();

  const float4* src = (const float4*)(cls + (size_t)n * HW) + blockIdx.x * 2048;
  float4 A[8];
#pragma unroll
  for (int v = 0; v < 8; v++) A[v] = src[tid + v * 256];   // 8 loads in flight

  const u64 ltmask = (1ull << lane) - 1ull;
#pragma unroll
  for (int v = 0; v < 8; v++) {
    float ss[4] = {A[v].x, A[v].y, A[v].z, A[v].w};
#pragma unroll
    for (int c = 0; c < 4; c++) {
      float s = ss[c];
      bool pc = s > PREF_C;
      u64 m = __ballot(pc);
      if (m) {
        int ldr = __ffsll(m) - 1;
        u32 wb = 0;
        if (lane == ldr) wb = atomicAdd(&lcnt, (u32)__popcll(m));   // LDS atomic only
        wb = (u32)__shfl((int)wb, ldr, 64);
        if (pc) {
          u32 pos = wb + (u32)__popcll(m & ltmask);
          if (pos < SEGCAP) lbuf[pos] = make_key(s, (u32)((blockIdx.x * 2048 + tid + v * 256) * 4 + c));
        }
      }
    }
  }
  __syncthreads();
  const int seg = n * NBLK + blockIdx.x;
  if (tid == 0) pcnt[seg] = (lcnt > SEGCAP) ? 0xFFFFFFFFu : lcnt;
  u32 c = lcnt < SEGCAP ? lcnt : (u32)SEGCAP;
  u64* pc = pcand + (size_t)seg * SEGCAP;
  for (u32 i = tid; i < c; i += 256) pc[i] = lbuf[i];
}

// reg-chain bitonic levels for stage k (jstart <= 64, via shuffles, no barriers)
#define REGCHAIN(K, JSTART) do {                                            \
    const bool desc_ = ((tid & ((K) >> 1)) == 0);                           \
    for (int j_ = (JSTART); j_ >= 2; j_ >>= 1) {                            \
      int h_ = j_ >> 1;                                                     \
      bool low_ = (tid & h_) == 0;                                          \
      u64 p0_ = shflxor64(e0, h_), p1_ = shflxor64(e1, h_);                 \
      bool tm_ = (low_ == desc_);                                           \
      e0 = tm_ ? (e0 > p0_ ? e0 : p0_) : (e0 < p0_ ? e0 : p0_);             \
      e1 = tm_ ? (e1 > p1_ ? e1 : p1_) : (e1 < p1_ ? e1 : p1_);             \
    }                                                                       \
    { u64 lo_ = e0 < e1 ? e0 : e1, hi_ = e0 < e1 ? e1 : e0;                 \
      e0 = desc_ ? hi_ : lo_; e1 = desc_ ? lo_ : hi_; }                     \
  } while (0)

// ---------- kernel 2: gather candidates + sort; write top-1024 keys ----------
__global__ __launch_bounds__(1024) void sort_kernel(const float* __restrict__ cls,
                                                    const u32* __restrict__ pcnt,
                                                    const u64* __restrict__ pcand,
                                                    u64* __restrict__ skeys) {
  __shared__ u64 skey[CANDCAP];        // 16 KB
  __shared__ u32 scnt[NBLK];
  __shared__ u32 soff[NBLK];
  __shared__ u32 bs[NBINS];            // fallback only
  __shared__ u32 stmp[64];
  __shared__ int stbin;
  __shared__ u32 sflag, sfc;

  const int n = blockIdx.x;
  const int tid = threadIdx.x;
  const int lane = tid & 63;
  const u64 ltmask = (1ull << lane) - 1ull;

  if (tid < NBLK) scnt[tid] = pcnt[n * NBLK + tid];
  skey[tid] = 0ull; skey[tid + 1024] = 0ull;
  if (tid == 0) sfc = 0;
  __syncthreads();
  if (tid == 0) {
    u32 f = 0, off = 0;
    for (int s = 0; s < NBLK; s++) {
      u32 c = scnt[s];
      if (c == 0xFFFFFFFFu) { f = 1; c = 0; }
      soff[s] = off; off += c;
    }
    if (off < TOPK || off > CANDCAP) f = 1;   // prefilter unusable -> exact fallback
    sflag = f;
  }
  __syncthreads();

  if (sflag == 0) {
    // direct placement: prefix offsets known, no atomics
    for (int s = 0; s < NBLK; s++) {
      u32 c = scnt[s];
      if (tid < c) skey[soff[s] + tid] = pcand[(size_t)(n * NBLK + s) * SEGCAP + tid];
    }
  } else {
    // exact fallback (dead path for bench input): LDS histogram + threshold + collect
    for (int i = tid; i < NBINS; i += 1024) bs[i] = 0;
    __syncthreads();
    const float* ci = cls + (size_t)n * HW;
    for (int base = 0; base < HW; base += 1024) {
      float s = ci[base + tid];
      if (s > THRESH) atomicAdd(&bs[bin_of(s)], 1u);
    }
    __syncthreads();
    if (tid < 64) {
      u32 cs = 0;
#pragma unroll
      for (int k2 = 0; k2 < 8; k2++) cs += bs[lane * 8 + k2];
      u32 s = cs;
#pragma unroll
      for (int d = 1; d < 64; d <<= 1) {
        u32 v = (u32)__shfl_down((int)s, d, 64);
        if (lane + d < 64) s += v;
      }
      stmp[lane] = s;
      u64 mask = __ballot(s >= TOPK);
      if (lane == 0) {
        int t = 0;
        if (mask) {
          int L = 63 - __clzll(mask);
          u32 acc = (L < 63) ? stmp[L + 1] : 0;
          for (int b = L * 8 + 7; b >= L * 8; b--) {
            acc += bs[b];
            if (acc >= TOPK) { t = b; break; }
          }
        }
        stbin = t;
      }
    }
    __syncthreads();
    const int t = stbin;
    for (int base = 0; base < HW; base += 1024) {
      int i = base + tid;
      float s = ci[i];
      bool p = (s > THRESH) && (bin_of(s) >= t);
      u64 m = __ballot(p);
      if (m) {
        int ldr = __ffsll(m) - 1;
        u32 wb = 0;
        if (lane == ldr) wb = atomicAdd(&sfc, (u32)__popcll(m));
        wb = (u32)__shfl((int)wb, ldr, 64);
        if (p) { u32 pos = wb + (u32)__popcll(m & ltmask); if (pos < CANDCAP) skey[pos] = make_key(s, (u32)i); }
      }
    }
  }
  __syncthreads();

  // hybrid bitonic sort (2048 keys, 2/thread; shfl for j<=64, LDS for j>=128)
  {
    u64 e0 = skey[2 * tid], e1 = skey[2 * tid + 1];
    REGCHAIN(2, 1); REGCHAIN(4, 2); REGCHAIN(8, 4); REGCHAIN(16, 8);
    REGCHAIN(32, 16); REGCHAIN(64, 32); REGCHAIN(128, 64);
    for (int k = 256; k <= CANDCAP; k <<= 1) {
      skey[2 * tid] = e0; skey[2 * tid + 1] = e1;
      __syncthreads();
      for (int j = k >> 1; j >= 128; j >>= 1) {
        int i = ((tid & ~(j - 1)) << 1) | (tid & (j - 1));
        u64 a = skey[i], b = skey[i + j];
        bool desc = ((i & k) == 0);
        if (desc ? (a < b) : (a > b)) { skey[i] = b; skey[i + j] = a; }
        __syncthreads();
      }
      e0 = skey[2 * tid]; e1 = skey[2 * tid + 1];
      REGCHAIN(k, 64);
    }
    skey[2 * tid] = e0; skey[2 * tid + 1] = e1;
    __syncthreads();
  }

  if (tid < KPAD) skeys[(size_t)n * KPAD + tid] = skey[tid];
}

// ---------- kernel 3: parallel gather + decode (chip-wide scattered loads) ----------
__global__ __launch_bounds__(128) void decode_kernel(const float* __restrict__ reg,
                                                     const u64* __restrict__ skeys,
                                                     float4* __restrict__ gboxes) {
  const int n = blockIdx.y;
  const int s8 = blockIdx.x;
  const int tid = threadIdx.x;
  const int k = s8 * 128 + tid;
  u64 key = skeys[(size_t)n * KPAD + k];
  float x0 = 0.f, y0 = 0.f, x1 = 0.f, y1 = 0.f;
  if (key != 0ull && k < TOPK) {
    u32 idx = ~(u32)(key & 0xFFFFFFFFull);
    int iy = (int)idx / WID;
    int ix = (int)idx - iy * WID;
    float xx = (float)ix * 4.0f;
    float yy = (float)iy * 4.0f;
    const float* rb = reg + (size_t)n * 4 * HW;
    float r0 = rb[idx];
    float r1 = rb[HW + idx];
    float r2 = rb[2 * HW + idx];
    float r3 = rb[3 * HW + idx];
    y0 = yy - r0; x1 = xx + r1; y1 = yy + r2; x0 = xx - r3;
  }
  gboxes[(size_t)n * KPAD + k] = make_float4(x0, y0, x1, y1);
}

// ---------- kernel 4: fused valid-compact NMS (matrix in LDS + bit-op resolve) + output ----------
// Exactness: boxes with w<0 or h<0 (or s<=0.05, or rank>=1000) have keep=false from the start in
// the reference and can never suppress (clipped area/intersection = 0 -> iou = 0 <= 0.4). Greedy
// NMS over the rank-ordered subsequence of VALID boxes is therefore exactly equivalent.
__global__ __launch_bounds__(1024) void nmsv_kernel(const float4* __restrict__ gboxes,
                                                    const u64* __restrict__ skeys,
                                                    float* __restrict__ out) {
  __shared__ float4 vbox[KPAD];        // 16 KB compacted valid boxes (rank order)
  __shared__ float varea[KPAD];        // 4 KB
  __shared__ u64 mlds[136 * 64];       // 68 KB suppression triangle (worst case 16 chunks)
  __shared__ u32 wcnt[16], woff[16];
  __shared__ int pc[136], pk[136];
  __shared__ int sV, snch, snp;
  __shared__ u64 keepsh[16], srem[16];

  const int n = blockIdx.x;
  const int tid = threadIdx.x;
  const int lane = tid & 63;
  const int w = tid >> 6;
  const u64 ltmask = (1ull << lane) - 1ull;

  // ---- load + validity + zero-fill ----
  u64 key = skeys[(size_t)n * KPAD + tid];
  float4 b = gboxes[(size_t)n * KPAD + tid];
  float s = __uint_as_float((u32)(key >> 32) & 0x7FFFFFFFu);
  bool vb = (tid < TOPK) && (s > THRESH) && (b.z - b.x >= 0.0f) && (b.w - b.y >= 0.0f);
  vbox[tid] = make_float4(0.f, 0.f, 0.f, 0.f);
  varea[tid] = 0.0f;
  u64 vm = __ballot(vb);
  if (lane == 0) wcnt[w] = (u32)__popcll(vm);
  if (tid < 16) { srem[tid] = 0ull; keepsh[tid] = 0ull; }
  __syncthreads();
  if (tid == 0) {
    u32 off = 0;
    for (int i = 0; i < 16; i++) { woff[i] = off; off += wcnt[i]; }
    int V = (int)off;
    int nch = (V + 63) >> 6;
    sV = V; snch = nch; snp = nch * (nch + 1) / 2;
  }
  __syncthreads();
  const int V = sV, nch = snch, npairs = snp;

  // ---- compact (rank order preserved); build pair->(c,k) tables ----
  int pos = -1;
  if (vb) {
    pos = (int)(woff[w] + (u32)__popcll(vm & ltmask));
    vbox[pos] = b;
    varea[pos] = area_of(b.x, b.y, b.z, b.w);
  }
  if (tid < npairs) {
    int p = tid, c = 0, base = 0;
    while (p >= base + (nch - c)) { base += nch - c; c++; }
    pc[tid] = c; pk[tid] = c + (p - base);
  }
  __syncthreads();

  // ---- matrix: row r of pair p -> bit j = iou(box_{64*k+i}, box_{64*c+j}) > T ----
  for (int r = w; r < npairs * 64; r += 16) {
    int p = r >> 6, i = r & 63;
    int c = pc[p], k = pk[p];
    float4 rbx = vbox[k * 64 + i];          // LDS broadcast
    float rarea = varea[k * 64 + i];
    float4 cbx = vbox[c * 64 + lane];
    float carea = varea[c * 64 + lane];
    bool pred = iou_gt(rbx.x, rbx.y, rbx.z, rbx.w, rarea,
                       cbx.x, cbx.y, cbx.z, cbx.w, carea);
    u64 m = __ballot(pred);
    if (lane == 0) mlds[r] = m;
  }
  __syncthreads();

  // ---- greedy resolve (wave 0; pure bit-ops) ----
  if (tid < 64) {
    for (int c = 0; c < nch; c++) {
      int pbase = c * nch - (c * (c - 1)) / 2 - c;    // p(c,k) = pbase + k
      u64 diag = mlds[(pbase + c) * 64 + lane];
      u64 ainit = (V >= (c + 1) * 64) ? ~0ull
                : ((V > c * 64) ? ((1ull << (V - c * 64)) - 1ull) : 0ull);
      u64 alive;
      {
        u64 a = ainit & ~srem[c];
        u32 alo2 = __builtin_amdgcn_readfirstlane((u32)a);
        u32 ahi2 = __builtin_amdgcn_readfirstlane((u32)(a >> 32));
        alive = ((u64)ahi2 << 32) | alo2;
      }
      u32 rlo = (u32)diag, rhi = (u32)(diag >> 32);
      u64 cur = alive;
      while (cur) {
        int i = __ffsll(cur) - 1;
        u32 rl = __builtin_amdgcn_readlane(rlo, i);
        u32 rh = __builtin_amdgcn_readlane(rhi, i);
        u64 rowi = ((u64)rh << 32) | rl;
        u64 lowmask = (i == 63) ? ~0ull : ((1ull << (i + 1)) - 1ull);
        rowi &= ~lowmask;                            // suppress only later boxes
        alive &= ~rowi;
        cur &= ~rowi;
        cur &= cur - 1;
      }
      if (lane == 0) keepsh[c] = alive;
      const u64 K = alive;
      for (int k = c + 1; k < nch; k++) {
        bool sup = (mlds[(pbase + k) * 64 + lane] & K) != 0ull;
        u64 mres = __ballot(sup);
        if (lane == 0) srem[k] |= mres;
      }
    }
  }
  __syncthreads();

  // ---- output (each thread owns its rank; pos maps to compacted keep bit) ----
  u64 kb = (vb && pos >= 0) ? ((keepsh[pos >> 6] >> (pos & 63)) & 1ull) : 0ull;
  if (tid < TOPK) {
    float f = (float)kb;
    size_t ob = (size_t)n * (TOPK * 5) + (size_t)tid * 5;
    out[ob + 0] = kb ? b.x : 0.0f;
    out[ob + 1] = kb ? b.y : 0.0f;
    out[ob + 2] = kb ? b.z : 0.0f;
    out[ob + 3] = kb ? b.w : 0.0f;
    out[ob + 4] = kb ? s : 0.0f;
    out[(size_t)NIMG * TOPK * 5 + (size_t)n * TOPK + tid] = f;
  }
}

extern "C" void kernel_launch(void* const* d_in, const int* in_sizes, int n_in,
                              void* d_out, int out_size, void* d_ws, size_t ws_size,
                              hipStream_t stream) {
  const float* cls = (const float*)d_in[0];   // (32,1,384,384) f32
  const float* reg = (const float*)d_in[1];   // (32,4,384,384) f32
  float* out = (float*)d_out;                 // 160000 (out) + 32000 (keep) f32

  uint8_t* ws = (uint8_t*)d_ws;
  u32* pcnt = (u32*)(ws + PCNT_OFF);
  u64* pcand = (u64*)(ws + PCAND_OFF);
  u64* skeys = (u64*)(ws + SKEYS_OFF);
  float4* gboxes = (float4*)(ws + BOXES_OFF);

  scan_kernel<<<dim3(NBLK, NIMG), 256, 0, stream>>>(cls, pcnt, pcand);
  sort_kernel<<<NIMG, 1024, 0, stream>>>(cls, pcnt, pcand, skeys);
  decode_kernel<<<dim3(8, NIMG), 128, 0, stream>>>(reg, skeys, gboxes);
  nmsv_kernel<<<NIMG, 1024, 0, stream>>>(gboxes, skeys, out);
}